// Round 7
// baseline (145.300 us; speedup 1.0000x reference)
//
#include <hip/hip_runtime.h>

#define NN  512    // data grid / coefficient count per axis
#define NE  1024   // eval points per axis
#define NBC 64     // batch * channels
#define WH  8      // truncated-inverse half width
#define WT  17     // 2*WH+1 taps
#define YT  16     // y-tile per eval block

// ================= compile-time table generation =================
// Mirrors the reference: x = float32 linspace(-1,1,512); knots via float32
// cumsum sliding mean; basis via de Boor in double; banded LU in double;
// truncated inverse band Gb (half-width 8) for BOTH solve directions; and
// W3 = the 4-tap eval basis re-anchored to a per-quad 16B-aligned 12-tap
// window so runtime register indexing is fully static.

struct Tables {
  float Gb[NN][WT];      // truncated A^-1 band
  int   espan[NE];
  float ebas[NE * 4];    // y-combine weights (float4-aligned)
  float W3[NE][12];      // anchored 4-tap x-filter (zeros elsewhere)
};

constexpr int cfindspan(double u, const float* t) {
  if (u >= (double)t[NN]) return NN - 1;          // t[512] == 1.0
  int lo = 3, hi = NN - 1;
  while (lo < hi) {
    int mid = (lo + hi + 1) >> 1;
    if ((double)t[mid] <= u) lo = mid; else hi = mid - 1;
  }
  return lo;
}

constexpr void cdeboor4(double u, const float* t, int s, double* N) {
  double left[4] = {}, right[4] = {};
  N[0] = 1.0; N[1] = 0.0; N[2] = 0.0; N[3] = 0.0;
  for (int d = 1; d <= 3; ++d) {
    left[d]  = u - (double)t[s + 1 - d];
    right[d] = (double)t[s + d] - u;
    double saved = 0.0;
    for (int r = 0; r < d; ++r) {
      double temp = N[r] / (right[r + 1] + left[d - r]);
      N[r] = saved + right[r + 1] * temp;
      saved = left[d - r] * temp;
    }
    N[d] = saved;
  }
}

constexpr Tables make_tables() {
  Tables T{};
  float x[NN] = {};
  for (int i = 0; i < NN; ++i) x[i] = (float)(-1.0 + (2.0 * i) / 511.0);
  x[0] = -1.0f; x[NN - 1] = 1.0f;
  float t[NN + 4] = {};
  {
    float cs[NN + 1] = {};
    for (int i = 0; i < NN; ++i) cs[i + 1] = cs[i] + x[i];
    for (int i = 0; i < NN - 4; ++i) t[4 + i] = (cs[4 + i] - cs[1 + i]) / 3.0f;
    for (int i = 0; i < 4; ++i) { t[i] = -1.0f; t[NN + i] = 1.0f; }
  }
  double W[NN][7] = {};
  for (int r = 0; r < NN; ++r) {
    double u = (double)x[r];
    int s = cfindspan(u, t);
    double N[4] = {};
    cdeboor4(u, t, s, N);
    for (int dd = 0; dd < 4; ++dd) W[r][s - r + dd] += N[dd];
  }
  for (int r = 0; r < NN; ++r) {
    double rd = 1.0 / W[r][3];
    for (int k = 1; k <= 3; ++k) {
      if (r + k < NN) {
        double l = W[r + k][3 - k] * rd;
        W[r + k][3 - k] = l;
        for (int cc = 1; cc <= 3; ++cc) W[r + k][3 - k + cc] -= l * W[r][3 + cc];
      }
    }
  }
  // truncated inverse band
  double Gbd[NN][WT] = {};
  double tv[WT] = {};
  for (int pass = 0; pass < 3; ++pass) {
    const int ylo = (pass == 0) ? 0 : (pass == 1) ? 480 : 256;
    const int yhi = (pass == 0) ? 32 : (pass == 1) ? 512 : 257;
    for (int y = ylo; y < yhi; ++y) {
      double wv[21] = {};
      int rend = y + 20; if (rend > NN - 1) rend = NN - 1;
      wv[0] = 1.0;
      for (int r = y + 1; r <= rend; ++r) {
        double acc = 0.0;
        if (r - 1 >= y) acc += W[r][2] * wv[r - 1 - y];
        if (r - 2 >= y) acc += W[r][1] * wv[r - 2 - y];
        if (r - 3 >= y) acc += W[r][0] * wv[r - 3 - y];
        wv[r - y] = -acc;
      }
      double g[29] = {};
      int glo = y - WH; if (glo < 0) glo = 0;
      for (int r = rend; r >= glo; --r) {
        double acc = (r >= y) ? wv[r - y] : 0.0;
        if (r + 1 <= rend) acc -= W[r][4] * g[r + 1 - (y - WH)];
        if (r + 2 <= rend) acc -= W[r][5] * g[r + 2 - (y - WH)];
        if (r + 3 <= rend) acc -= W[r][6] * g[r + 3 - (y - WH)];
        g[r - (y - WH)] = acc / W[r][3];
      }
      if (pass == 2) {
        for (int d = 0; d < WT; ++d) tv[d] = g[16 - d];
      } else {
        int jlo = y - WH; if (jlo < 0) jlo = 0;
        int jhi = y + WH; if (jhi > NN - 1) jhi = NN - 1;
        for (int j = jlo; j <= jhi; ++j) {
          const bool bdry = (pass == 0) ? (j < 24) : (j >= 488);
          if (bdry) Gbd[j][y - j + WH] = g[j - (y - WH)];
        }
      }
    }
  }
  for (int j = 24; j < 488; ++j)
    for (int d = 0; d < WT; ++d) Gbd[j][d] = tv[d];
  for (int j = 0; j < NN; ++j)
    for (int d = 0; d < WT; ++d) T.Gb[j][d] = (float)Gbd[j][d];
  // eval-point basis + anchored 12-tap x-filter
  int    s_all[NE] = {};
  double dN[NE][4] = {};
  for (int i = 0; i < NE; ++i) {
    float xe = (float)(-1.0 + (2.0 * i) / 1023.0);
    if (i == 0) xe = -1.0f;
    if (i == NE - 1) xe = 1.0f;
    double u = (double)xe;
    int s = cfindspan(u, t);
    double N[4] = {};
    cdeboor4(u, t, s, N);
    s_all[i] = s;
    for (int k = 0; k < 4; ++k) dN[i][k] = N[k];
    T.espan[i] = s;
    T.ebas[i * 4 + 0] = (float)N[0];
    T.ebas[i * 4 + 1] = (float)N[1];
    T.ebas[i * 4 + 2] = (float)N[2];
    T.ebas[i * 4 + 3] = (float)N[3];
  }
  // W3: out[x] = sum_m W3[x][m] * R[a3 + m], a3 = (s_all[quad0]-3)&~3.
  // Offsets s_all[x]-3+k-a3 are in [0,8] (quad span drift <= 2), < 12.
  for (int xx = 0; xx < NE; ++xx) {
    const int a3 = (s_all[(xx >> 2) << 2] - 3) & ~3;
    for (int k = 0; k < 4; ++k) {
      const int m = s_all[xx] - 3 + k - a3;
      T.W3[xx][m] = (float)dN[xx][k];
    }
  }
  return T;
}

__constant__ Tables g_tab = make_tables();

// ------------- K1: full 2D banded solve, one pass -------------
// CoefT[bc][j][i] = sum_{d,e} Gb[i][d]*Gb[j][e]*Z[bc][i-8+d][j-8+e]
// Per block: 64x64 coef tile; load 80x80 Z window; stage1 (y-taps) into
// transposed LDS; stage2 (x-taps); coalesced float4 writes.

__global__ __launch_bounds__(256) void k_solve2d(const float* __restrict__ Z,
                                                 float* __restrict__ CT) {
  const int it = blockIdx.x * 64;
  const int jt = blockIdx.y * 64;
  const int bc = blockIdx.z;
  const float* __restrict__ src = Z + (size_t)bc * (NN * NN);
  __shared__ float in[80][88];   // Z[i window][j window], i rows
  __shared__ float At[64][89];   // stage-1 result TRANSPOSED: At[jc][ii]
  const int tid = threadIdx.x;
  const int q4 = (tid & 15) * 4;    // quad base (jc for stage1, ic for stage2)

  // load 80x80 window (zero-pad outside grid; Gb taps there are 0)
  for (int u = tid; u < 1600; u += 256) {
    const int r = u / 20, c4 = (u % 20) * 4;
    const int gi = it - 8 + r;
    const int gj = jt - 8 + c4;
    float4 v;
    if (gi >= 0 && gi < NN && gj >= 0 && gj + 4 <= NN) {
      v = *(const float4*)&src[(size_t)gi * NN + gj];
    } else if (gi >= 0 && gi < NN) {
      float e0 = (gj + 0 >= 0 && gj + 0 < NN) ? src[(size_t)gi * NN + gj + 0] : 0.f;
      float e1 = (gj + 1 >= 0 && gj + 1 < NN) ? src[(size_t)gi * NN + gj + 1] : 0.f;
      float e2 = (gj + 2 >= 0 && gj + 2 < NN) ? src[(size_t)gi * NN + gj + 2] : 0.f;
      float e3 = (gj + 3 >= 0 && gj + 3 < NN) ? src[(size_t)gi * NN + gj + 3] : 0.f;
      v = make_float4(e0, e1, e2, e3);
    } else {
      v = make_float4(0.f, 0.f, 0.f, 0.f);
    }
    *(float4*)&in[r][c4] = v;
  }

  { // stage 1: 17-tap along j, all 80 i-rows; write transposed
    float cy[4][WT];
    #pragma unroll
    for (int q = 0; q < 4; ++q)
      #pragma unroll
      for (int d = 0; d < WT; ++d)
        cy[q][d] = g_tab.Gb[jt + q4 + q][d];
    __syncthreads();
    #pragma unroll 1
    for (int p = 0; p < 5; ++p) {
      const int ii = p * 16 + (tid >> 4);
      float w[20];
      #pragma unroll
      for (int e = 0; e < 5; ++e)
        *(float4*)&w[e * 4] = *(const float4*)&in[ii][q4 + e * 4];
      float4 a = make_float4(0.f, 0.f, 0.f, 0.f);
      #pragma unroll
      for (int d = 0; d < WT; ++d) {
        a.x += cy[0][d] * w[0 + d];
        a.y += cy[1][d] * w[1 + d];
        a.z += cy[2][d] * w[2 + d];
        a.w += cy[3][d] * w[3 + d];
      }
      At[q4 + 0][ii] = a.x;
      At[q4 + 1][ii] = a.y;
      At[q4 + 2][ii] = a.z;
      At[q4 + 3][ii] = a.w;
    }
  }
  { // stage 2: 17-tap along i; coalesced writes
    float cx[4][WT];
    #pragma unroll
    for (int q = 0; q < 4; ++q)
      #pragma unroll
      for (int d = 0; d < WT; ++d)
        cx[q][d] = g_tab.Gb[it + q4 + q][d];
    __syncthreads();
    float* __restrict__ dst = CT + (size_t)bc * (NN * NN);
    #pragma unroll 1
    for (int p = 0; p < 4; ++p) {
      const int jc = p * 16 + (tid >> 4);
      float w[20];
      #pragma unroll
      for (int e = 0; e < 5; ++e)
        *(float4*)&w[e * 4] = *(const float4*)&At[jc][q4 + e * 4];
      float4 a = make_float4(0.f, 0.f, 0.f, 0.f);
      #pragma unroll
      for (int d = 0; d < WT; ++d) {
        a.x += cx[0][d] * w[0 + d];
        a.y += cx[1][d] * w[1 + d];
        a.z += cx[2][d] * w[2 + d];
        a.w += cx[3][d] * w[3 + d];
      }
      *(float4*)&dst[(size_t)(jt + jc) * NN + it + q4] = a;
    }
  }
}

// ------------- K2: y-tiled eval, 4-tap y combine + anchored 12-tap x -------------
// Per block: 16 output rows; 14-row CoefT window loaded once; per y-pair:
//   R[i] = 4-row combine  ->  out[x] = 12-tap static dot on R.
// Double-buffered Rb, one barrier per pair, all register indexing static.

__global__ __launch_bounds__(256) void k_eval5(const float* __restrict__ CT,
                                               float* __restrict__ out) {
  const int y0 = blockIdx.x * YT;
  const int bc = blockIdx.y;
  const float* __restrict__ S = CT + (size_t)bc * (NN * NN);
  __shared__ float rows[14][NN];                 // 28 KB row window
  __shared__ __align__(16) float Rb[2][2][528];  // [dbuf][row-of-pair][i], pad zeros at [512,528)
  const int tid = threadIdx.x;
  const int rlo = g_tab.espan[y0] - 3;

  for (int u = tid; u < 14 * 128; u += 256) {
    const int rr = u >> 7, c4 = (u & 127) * 4;
    const int r = rlo + rr;
    float4 v = (r < NN) ? *(const float4*)&S[(size_t)r * NN + c4]
                        : make_float4(0.f, 0.f, 0.f, 0.f);
    *(float4*)&rows[rr][c4] = v;
  }
  if (tid < 64) Rb[(tid >> 5) & 1][(tid >> 4) & 1][512 + (tid & 15)] = 0.f;

  // hoisted per-thread constants
  const int x0 = tid * 4;
  const int a3 = (g_tab.espan[x0] - 3) & ~3;     // 16B-aligned window base
  float tp[4][12];
  #pragma unroll
  for (int e = 0; e < 4; ++e)
    #pragma unroll
    for (int m = 0; m < 12; ++m)
      tp[e][m] = g_tab.W3[x0 + e][m];
  const int p2 = tid * 2;

  auto do_R = [&](int k) {
    const int buf = k & 1;
    #pragma unroll
    for (int hh = 0; hh < 2; ++hh) {
      const int y = y0 + 2 * k + hh;
      const int ry = g_tab.espan[y] - rlo;       // 3..11 by construction
      const float4 wy = *(const float4*)&g_tab.ebas[y * 4];
      float2 r0 = *(const float2*)&rows[ry - 3][p2];
      float2 r1 = *(const float2*)&rows[ry - 2][p2];
      float2 r2 = *(const float2*)&rows[ry - 1][p2];
      float2 r3 = *(const float2*)&rows[ry    ][p2];
      float2 acc;
      acc.x = wy.x * r0.x + wy.y * r1.x + wy.z * r2.x + wy.w * r3.x;
      acc.y = wy.x * r0.y + wy.y * r1.y + wy.z * r2.y + wy.w * r3.y;
      *(float2*)&Rb[buf][hh][p2] = acc;
    }
  };

  __syncthreads();
  do_R(0);
  __syncthreads();
  #pragma unroll 1
  for (int k = 0; k < YT / 2; ++k) {
    if (k + 1 < YT / 2) do_R(k + 1);             // fill other buffer
    float* __restrict__ O = out + ((size_t)bc * NE + (y0 + 2 * k)) * NE;
    #pragma unroll
    for (int hh = 0; hh < 2; ++hh) {
      float w[12];
      #pragma unroll
      for (int e = 0; e < 3; ++e)
        *(float4*)&w[e * 4] = *(const float4*)&Rb[k & 1][hh][a3 + e * 4];
      float4 o;
      #pragma unroll
      for (int e = 0; e < 4; ++e) {
        float a0 = 0.f, a1 = 0.f;
        #pragma unroll
        for (int m = 0; m < 12; m += 2) {
          a0 += tp[e][m]     * w[m];
          a1 += tp[e][m + 1] * w[m + 1];
        }
        (&o.x)[e] = a0 + a1;
      }
      *(float4*)&O[(size_t)hh * NE + x0] = o;
    }
    __syncthreads();
  }
}

// ---------------- host launcher ----------------

extern "C" void kernel_launch(void* const* d_in, const int* in_sizes, int n_in,
                              void* d_out, int out_size, void* d_ws, size_t ws_size,
                              hipStream_t stream) {
  (void)in_sizes; (void)n_in; (void)out_size; (void)ws_size;
  const float* Z = (const float*)d_in[0];
  float* out = (float*)d_out;
  float* CT = (float*)d_ws;      // 64 MB (must not alias out)

  k_solve2d<<<dim3(8, 8, NBC),  256, 0, stream>>>(Z,  CT);   // full 2D banded solve
  k_eval5  <<<dim3(NE / YT, NBC), 256, 0, stream>>>(CT, out); // 4-tap y + 12-tap x eval
}

// Round 8
// 137.525 us; speedup vs baseline: 1.0565x; 1.0565x over previous
//
#include <hip/hip_runtime.h>

#define NN  512    // data grid / coefficient count per axis
#define NE  1024   // eval points per axis
#define NBC 64     // batch * channels
#define WH  8      // truncated-inverse half width
#define WT  17     // 2*WH+1 taps
#define YT  16     // y-tile per eval block

// ================= compile-time table generation =================
// Mirrors the reference: x = float32 linspace(-1,1,512); knots via float32
// cumsum sliding mean; basis via de Boor in double; banded LU in double;
// truncated inverse band Gb (half-width 8) for BOTH solve directions; and
// W3 = the 4-tap eval basis re-anchored to a per-quad 16B-aligned 12-tap
// window so runtime register indexing is fully static.

struct Tables {
  float Gb[NN][WT];      // truncated A^-1 band
  int   espan[NE];
  float ebas[NE * 4];    // y-combine weights (float4-aligned)
  float W3[NE][12];      // anchored 4-tap x-filter (zeros elsewhere)
};

constexpr int cfindspan(double u, const float* t) {
  if (u >= (double)t[NN]) return NN - 1;          // t[512] == 1.0
  int lo = 3, hi = NN - 1;
  while (lo < hi) {
    int mid = (lo + hi + 1) >> 1;
    if ((double)t[mid] <= u) lo = mid; else hi = mid - 1;
  }
  return lo;
}

constexpr void cdeboor4(double u, const float* t, int s, double* N) {
  double left[4] = {}, right[4] = {};
  N[0] = 1.0; N[1] = 0.0; N[2] = 0.0; N[3] = 0.0;
  for (int d = 1; d <= 3; ++d) {
    left[d]  = u - (double)t[s + 1 - d];
    right[d] = (double)t[s + d] - u;
    double saved = 0.0;
    for (int r = 0; r < d; ++r) {
      double temp = N[r] / (right[r + 1] + left[d - r]);
      N[r] = saved + right[r + 1] * temp;
      saved = left[d - r] * temp;
    }
    N[d] = saved;
  }
}

constexpr Tables make_tables() {
  Tables T{};
  float x[NN] = {};
  for (int i = 0; i < NN; ++i) x[i] = (float)(-1.0 + (2.0 * i) / 511.0);
  x[0] = -1.0f; x[NN - 1] = 1.0f;
  float t[NN + 4] = {};
  {
    float cs[NN + 1] = {};
    for (int i = 0; i < NN; ++i) cs[i + 1] = cs[i] + x[i];
    for (int i = 0; i < NN - 4; ++i) t[4 + i] = (cs[4 + i] - cs[1 + i]) / 3.0f;
    for (int i = 0; i < 4; ++i) { t[i] = -1.0f; t[NN + i] = 1.0f; }
  }
  double W[NN][7] = {};
  for (int r = 0; r < NN; ++r) {
    double u = (double)x[r];
    int s = cfindspan(u, t);
    double N[4] = {};
    cdeboor4(u, t, s, N);
    for (int dd = 0; dd < 4; ++dd) W[r][s - r + dd] += N[dd];
  }
  for (int r = 0; r < NN; ++r) {
    double rd = 1.0 / W[r][3];
    for (int k = 1; k <= 3; ++k) {
      if (r + k < NN) {
        double l = W[r + k][3 - k] * rd;
        W[r + k][3 - k] = l;
        for (int cc = 1; cc <= 3; ++cc) W[r + k][3 - k + cc] -= l * W[r][3 + cc];
      }
    }
  }
  // truncated inverse band
  double Gbd[NN][WT] = {};
  double tv[WT] = {};
  for (int pass = 0; pass < 3; ++pass) {
    const int ylo = (pass == 0) ? 0 : (pass == 1) ? 480 : 256;
    const int yhi = (pass == 0) ? 32 : (pass == 1) ? 512 : 257;
    for (int y = ylo; y < yhi; ++y) {
      double wv[21] = {};
      int rend = y + 20; if (rend > NN - 1) rend = NN - 1;
      wv[0] = 1.0;
      for (int r = y + 1; r <= rend; ++r) {
        double acc = 0.0;
        if (r - 1 >= y) acc += W[r][2] * wv[r - 1 - y];
        if (r - 2 >= y) acc += W[r][1] * wv[r - 2 - y];
        if (r - 3 >= y) acc += W[r][0] * wv[r - 3 - y];
        wv[r - y] = -acc;
      }
      double g[29] = {};
      int glo = y - WH; if (glo < 0) glo = 0;
      for (int r = rend; r >= glo; --r) {
        double acc = (r >= y) ? wv[r - y] : 0.0;
        if (r + 1 <= rend) acc -= W[r][4] * g[r + 1 - (y - WH)];
        if (r + 2 <= rend) acc -= W[r][5] * g[r + 2 - (y - WH)];
        if (r + 3 <= rend) acc -= W[r][6] * g[r + 3 - (y - WH)];
        g[r - (y - WH)] = acc / W[r][3];
      }
      if (pass == 2) {
        for (int d = 0; d < WT; ++d) tv[d] = g[16 - d];
      } else {
        int jlo = y - WH; if (jlo < 0) jlo = 0;
        int jhi = y + WH; if (jhi > NN - 1) jhi = NN - 1;
        for (int j = jlo; j <= jhi; ++j) {
          const bool bdry = (pass == 0) ? (j < 24) : (j >= 488);
          if (bdry) Gbd[j][y - j + WH] = g[j - (y - WH)];
        }
      }
    }
  }
  for (int j = 24; j < 488; ++j)
    for (int d = 0; d < WT; ++d) Gbd[j][d] = tv[d];
  for (int j = 0; j < NN; ++j)
    for (int d = 0; d < WT; ++d) T.Gb[j][d] = (float)Gbd[j][d];
  // eval-point basis + anchored 12-tap x-filter
  int    s_all[NE] = {};
  double dN[NE][4] = {};
  for (int i = 0; i < NE; ++i) {
    float xe = (float)(-1.0 + (2.0 * i) / 1023.0);
    if (i == 0) xe = -1.0f;
    if (i == NE - 1) xe = 1.0f;
    double u = (double)xe;
    int s = cfindspan(u, t);
    double N[4] = {};
    cdeboor4(u, t, s, N);
    s_all[i] = s;
    for (int k = 0; k < 4; ++k) dN[i][k] = N[k];
    T.espan[i] = s;
    T.ebas[i * 4 + 0] = (float)N[0];
    T.ebas[i * 4 + 1] = (float)N[1];
    T.ebas[i * 4 + 2] = (float)N[2];
    T.ebas[i * 4 + 3] = (float)N[3];
  }
  // W3: out[x] = sum_m W3[x][m] * R[a3 + m], a3 = (s_all[quad0]-3)&~3.
  // Offsets s_all[x]-3+k-a3 are in [0,8] (quad span drift <= 2), < 12.
  for (int xx = 0; xx < NE; ++xx) {
    const int a3 = (s_all[(xx >> 2) << 2] - 3) & ~3;
    for (int k = 0; k < 4; ++k) {
      const int m = s_all[xx] - 3 + k - a3;
      T.W3[xx][m] = (float)dN[xx][k];
    }
  }
  return T;
}

__constant__ Tables g_tab = make_tables();

// ------------- K1: full 2D banded solve, one pass -------------
// CoefT[bc][j][i] = sum_{d,e} Gb[i][d]*Gb[j][e]*Z[bc][i-8+d][j-8+e]
// Per block: 64x64 coef tile; load 80x80 Z window; stage1 (y-taps) into
// transposed LDS; stage2 (x-taps); coalesced float4 writes.

__global__ __launch_bounds__(256) void k_solve2d(const float* __restrict__ Z,
                                                 float* __restrict__ CT) {
  const int it = blockIdx.x * 64;
  const int jt = blockIdx.y * 64;
  const int bc = blockIdx.z;
  const float* __restrict__ src = Z + (size_t)bc * (NN * NN);
  __shared__ float in[80][88];   // Z[i window][j window], i rows
  __shared__ float At[64][89];   // stage-1 result TRANSPOSED: At[jc][ii]
  const int tid = threadIdx.x;
  const int q4 = (tid & 15) * 4;    // quad base (jc for stage1, ic for stage2)

  // load 80x80 window (zero-pad outside grid; Gb taps there are 0)
  for (int u = tid; u < 1600; u += 256) {
    const int r = u / 20, c4 = (u % 20) * 4;
    const int gi = it - 8 + r;
    const int gj = jt - 8 + c4;
    float4 v;
    if (gi >= 0 && gi < NN && gj >= 0 && gj + 4 <= NN) {
      v = *(const float4*)&src[(size_t)gi * NN + gj];
    } else if (gi >= 0 && gi < NN) {
      float e0 = (gj + 0 >= 0 && gj + 0 < NN) ? src[(size_t)gi * NN + gj + 0] : 0.f;
      float e1 = (gj + 1 >= 0 && gj + 1 < NN) ? src[(size_t)gi * NN + gj + 1] : 0.f;
      float e2 = (gj + 2 >= 0 && gj + 2 < NN) ? src[(size_t)gi * NN + gj + 2] : 0.f;
      float e3 = (gj + 3 >= 0 && gj + 3 < NN) ? src[(size_t)gi * NN + gj + 3] : 0.f;
      v = make_float4(e0, e1, e2, e3);
    } else {
      v = make_float4(0.f, 0.f, 0.f, 0.f);
    }
    *(float4*)&in[r][c4] = v;
  }

  { // stage 1: 17-tap along j, all 80 i-rows; write transposed
    float cy[4][WT];
    #pragma unroll
    for (int q = 0; q < 4; ++q)
      #pragma unroll
      for (int d = 0; d < WT; ++d)
        cy[q][d] = g_tab.Gb[jt + q4 + q][d];
    __syncthreads();
    #pragma unroll 1
    for (int p = 0; p < 5; ++p) {
      const int ii = p * 16 + (tid >> 4);
      float w[20];
      #pragma unroll
      for (int e = 0; e < 5; ++e)
        *(float4*)&w[e * 4] = *(const float4*)&in[ii][q4 + e * 4];
      float4 a = make_float4(0.f, 0.f, 0.f, 0.f);
      #pragma unroll
      for (int d = 0; d < WT; ++d) {
        a.x += cy[0][d] * w[0 + d];
        a.y += cy[1][d] * w[1 + d];
        a.z += cy[2][d] * w[2 + d];
        a.w += cy[3][d] * w[3 + d];
      }
      At[q4 + 0][ii] = a.x;
      At[q4 + 1][ii] = a.y;
      At[q4 + 2][ii] = a.z;
      At[q4 + 3][ii] = a.w;
    }
  }
  { // stage 2: 17-tap along i; coalesced writes
    float cx[4][WT];
    #pragma unroll
    for (int q = 0; q < 4; ++q)
      #pragma unroll
      for (int d = 0; d < WT; ++d)
        cx[q][d] = g_tab.Gb[it + q4 + q][d];
    __syncthreads();
    float* __restrict__ dst = CT + (size_t)bc * (NN * NN);
    #pragma unroll 1
    for (int p = 0; p < 4; ++p) {
      const int jc = p * 16 + (tid >> 4);
      float w[20];
      #pragma unroll
      for (int e = 0; e < 5; ++e)
        *(float4*)&w[e * 4] = *(const float4*)&At[jc][q4 + e * 4];
      float4 a = make_float4(0.f, 0.f, 0.f, 0.f);
      #pragma unroll
      for (int d = 0; d < WT; ++d) {
        a.x += cx[0][d] * w[0 + d];
        a.y += cx[1][d] * w[1 + d];
        a.z += cx[2][d] * w[2 + d];
        a.w += cx[3][d] * w[3 + d];
      }
      *(float4*)&dst[(size_t)(jt + jc) * NN + it + q4] = a;
    }
  }
}

// ------------- K2: BARRIER-FREE y-tiled eval -------------
// Per block: 16 output rows; 14-row CoefT window loaded once (single barrier).
// Each thread owns one x-quad; per y-pair it privately rebuilds its 12-float
// R window from rows[] (union <= 5 rows, wave-uniform branch), applies the
// anchored 12-tap x-filter, stores 2 float4. No syncs in the steady state.

__global__ __launch_bounds__(256) void k_eval6(const float* __restrict__ CT,
                                               float* __restrict__ out) {
  const int ytile = ((blockIdx.x & 7) << 3) | (blockIdx.x >> 3);  // XCD-chunked swizzle (64 tiles)
  const int y0 = ytile * YT;
  const int bc = blockIdx.y;
  const float* __restrict__ S = CT + (size_t)bc * (NN * NN);
  __shared__ float rows[14][524];   // 512 data + 12 zeroed pad (a3+11 <= 519)
  const int tid = threadIdx.x;
  const int rlo = g_tab.espan[y0] - 3;

  // load 14-row window (contiguous 28 KB of CT)
  for (int u = tid; u < 14 * 128; u += 256) {
    const int rr = u >> 7, c4 = (u & 127) * 4;
    const int r = rlo + rr;
    float4 v = (r < NN) ? *(const float4*)&S[(size_t)r * NN + c4]
                        : make_float4(0.f, 0.f, 0.f, 0.f);
    *(float4*)&rows[rr][c4] = v;
  }
  if (tid < 42) {   // zero the pad columns (poison could be NaN; NaN*0 = NaN)
    const int rr = tid / 3, c4 = 512 + (tid % 3) * 4;
    *(float4*)&rows[rr][c4] = make_float4(0.f, 0.f, 0.f, 0.f);
  }

  // hoisted per-thread constants
  const int x0 = tid * 4;
  const int a3 = (g_tab.espan[x0] - 3) & ~3;     // 16B-aligned window base
  float tp[4][12];
  #pragma unroll
  for (int e = 0; e < 4; ++e)
    #pragma unroll
    for (int m = 0; m < 12; ++m)
      tp[e][m] = g_tab.W3[x0 + e][m];

  __syncthreads();

  float* __restrict__ O0 = out + ((size_t)bc * NE + y0) * NE + x0;
  #pragma unroll 1
  for (int k = 0; k < YT / 2; ++k) {
    const int ya = y0 + 2 * k;
    const int ry0 = g_tab.espan[ya] - rlo;       // rows ry0-3..ry0 for ya
    const int ry1 = g_tab.espan[ya + 1] - rlo;   // in {ry0, ry0+1}
    const float4 wy0 = *(const float4*)&g_tab.ebas[ya * 4];
    const float4 wy1 = *(const float4*)&g_tab.ebas[(ya + 1) * 4];
    const int rb = ry0 - 3;                      // 0..8 (always in [0,13])
    float R0[12], R1[12];
    #pragma unroll
    for (int m = 0; m < 12; ++m) { R0[m] = 0.f; R1[m] = 0.f; }
    if (ry1 == ry0) {                            // wave-uniform scalar branch
      #pragma unroll
      for (int kk = 0; kk < 4; ++kk) {
        float wa[12];
        #pragma unroll
        for (int e = 0; e < 3; ++e)
          *(float4*)&wa[e * 4] = *(const float4*)&rows[rb + kk][a3 + e * 4];
        const float w0 = (&wy0.x)[kk], w1 = (&wy1.x)[kk];
        #pragma unroll
        for (int m = 0; m < 12; ++m) { R0[m] += w0 * wa[m]; R1[m] += w1 * wa[m]; }
      }
    } else {                                     // ry1 = ry0+1: union is 5 rows
      #pragma unroll
      for (int kk = 0; kk < 5; ++kk) {
        float wa[12];
        #pragma unroll
        for (int e = 0; e < 3; ++e)
          *(float4*)&wa[e * 4] = *(const float4*)&rows[rb + kk][a3 + e * 4];
        if (kk < 4) {
          const float w0 = (&wy0.x)[kk];
          #pragma unroll
          for (int m = 0; m < 12; ++m) R0[m] += w0 * wa[m];
        }
        if (kk > 0) {
          const float w1 = (&wy1.x)[kk - 1];
          #pragma unroll
          for (int m = 0; m < 12; ++m) R1[m] += w1 * wa[m];
        }
      }
    }
    float4 o0, o1;
    #pragma unroll
    for (int e = 0; e < 4; ++e) {
      float s0 = 0.f, s1 = 0.f;
      #pragma unroll
      for (int m = 0; m < 12; ++m) {
        s0 += tp[e][m] * R0[m];
        s1 += tp[e][m] * R1[m];
      }
      (&o0.x)[e] = s0;
      (&o1.x)[e] = s1;
    }
    *(float4*)&O0[(size_t)(2 * k)     * NE] = o0;
    *(float4*)&O0[(size_t)(2 * k + 1) * NE] = o1;
  }
}

// ---------------- host launcher ----------------

extern "C" void kernel_launch(void* const* d_in, const int* in_sizes, int n_in,
                              void* d_out, int out_size, void* d_ws, size_t ws_size,
                              hipStream_t stream) {
  (void)in_sizes; (void)n_in; (void)out_size; (void)ws_size;
  const float* Z = (const float*)d_in[0];
  float* out = (float*)d_out;
  float* CT = (float*)d_ws;      // 64 MB (must not alias out)

  k_solve2d<<<dim3(8, 8, NBC),    256, 0, stream>>>(Z,  CT);   // full 2D banded solve
  k_eval6  <<<dim3(NE / YT, NBC), 256, 0, stream>>>(CT, out);  // barrier-free eval
}

// Round 10
// 115.404 us; speedup vs baseline: 1.2591x; 1.1917x over previous
//
#include <hip/hip_runtime.h>

#define NN  512    // data grid / coefficient count per axis
#define NE  1024   // eval points per axis
#define NBC 64     // batch * channels
#define WH  8      // truncated-inverse half width
#define WT  17     // 2*WH+1 taps
#define YT  16     // y-tile per eval block

typedef float v4f __attribute__((ext_vector_type(4)));   // native vec for nontemporal builtins

// ================= compile-time table generation =================
// Mirrors the reference: x = float32 linspace(-1,1,512); knots via float32
// cumsum sliding mean; basis via de Boor in double; banded LU in double;
// truncated inverse band Gb (half-width 8) for BOTH solve directions; and
// W3 = the 4-tap eval basis re-anchored to a per-quad 16B-aligned 12-tap
// window so runtime register indexing is fully static.
// NOTE: Gb rows have EXACT ZEROS at tap positions whose source column falls
// outside [0,NN) — the solve kernel exploits this to replace boundary
// predication with address clamping.

struct Tables {
  float Gb[NN][WT];      // truncated A^-1 band
  int   espan[NE];
  float ebas[NE * 4];    // y-combine weights (float4-aligned)
  float W3[NE][12];      // anchored 4-tap x-filter (zeros elsewhere)
};

constexpr int cfindspan(double u, const float* t) {
  if (u >= (double)t[NN]) return NN - 1;          // t[512] == 1.0
  int lo = 3, hi = NN - 1;
  while (lo < hi) {
    int mid = (lo + hi + 1) >> 1;
    if ((double)t[mid] <= u) lo = mid; else hi = mid - 1;
  }
  return lo;
}

constexpr void cdeboor4(double u, const float* t, int s, double* N) {
  double left[4] = {}, right[4] = {};
  N[0] = 1.0; N[1] = 0.0; N[2] = 0.0; N[3] = 0.0;
  for (int d = 1; d <= 3; ++d) {
    left[d]  = u - (double)t[s + 1 - d];
    right[d] = (double)t[s + d] - u;
    double saved = 0.0;
    for (int r = 0; r < d; ++r) {
      double temp = N[r] / (right[r + 1] + left[d - r]);
      N[r] = saved + right[r + 1] * temp;
      saved = left[d - r] * temp;
    }
    N[d] = saved;
  }
}

constexpr Tables make_tables() {
  Tables T{};
  float x[NN] = {};
  for (int i = 0; i < NN; ++i) x[i] = (float)(-1.0 + (2.0 * i) / 511.0);
  x[0] = -1.0f; x[NN - 1] = 1.0f;
  float t[NN + 4] = {};
  {
    float cs[NN + 1] = {};
    for (int i = 0; i < NN; ++i) cs[i + 1] = cs[i] + x[i];
    for (int i = 0; i < NN - 4; ++i) t[4 + i] = (cs[4 + i] - cs[1 + i]) / 3.0f;
    for (int i = 0; i < 4; ++i) { t[i] = -1.0f; t[NN + i] = 1.0f; }
  }
  double W[NN][7] = {};
  for (int r = 0; r < NN; ++r) {
    double u = (double)x[r];
    int s = cfindspan(u, t);
    double N[4] = {};
    cdeboor4(u, t, s, N);
    for (int dd = 0; dd < 4; ++dd) W[r][s - r + dd] += N[dd];
  }
  for (int r = 0; r < NN; ++r) {
    double rd = 1.0 / W[r][3];
    for (int k = 1; k <= 3; ++k) {
      if (r + k < NN) {
        double l = W[r + k][3 - k] * rd;
        W[r + k][3 - k] = l;
        for (int cc = 1; cc <= 3; ++cc) W[r + k][3 - k + cc] -= l * W[r][3 + cc];
      }
    }
  }
  // truncated inverse band
  double Gbd[NN][WT] = {};
  double tv[WT] = {};
  for (int pass = 0; pass < 3; ++pass) {
    const int ylo = (pass == 0) ? 0 : (pass == 1) ? 480 : 256;
    const int yhi = (pass == 0) ? 32 : (pass == 1) ? 512 : 257;
    for (int y = ylo; y < yhi; ++y) {
      double wv[21] = {};
      int rend = y + 20; if (rend > NN - 1) rend = NN - 1;
      wv[0] = 1.0;
      for (int r = y + 1; r <= rend; ++r) {
        double acc = 0.0;
        if (r - 1 >= y) acc += W[r][2] * wv[r - 1 - y];
        if (r - 2 >= y) acc += W[r][1] * wv[r - 2 - y];
        if (r - 3 >= y) acc += W[r][0] * wv[r - 3 - y];
        wv[r - y] = -acc;
      }
      double g[29] = {};
      int glo = y - WH; if (glo < 0) glo = 0;
      for (int r = rend; r >= glo; --r) {
        double acc = (r >= y) ? wv[r - y] : 0.0;
        if (r + 1 <= rend) acc -= W[r][4] * g[r + 1 - (y - WH)];
        if (r + 2 <= rend) acc -= W[r][5] * g[r + 2 - (y - WH)];
        if (r + 3 <= rend) acc -= W[r][6] * g[r + 3 - (y - WH)];
        g[r - (y - WH)] = acc / W[r][3];
      }
      if (pass == 2) {
        for (int d = 0; d < WT; ++d) tv[d] = g[16 - d];
      } else {
        int jlo = y - WH; if (jlo < 0) jlo = 0;
        int jhi = y + WH; if (jhi > NN - 1) jhi = NN - 1;
        for (int j = jlo; j <= jhi; ++j) {
          const bool bdry = (pass == 0) ? (j < 24) : (j >= 488);
          if (bdry) Gbd[j][y - j + WH] = g[j - (y - WH)];
        }
      }
    }
  }
  for (int j = 24; j < 488; ++j)
    for (int d = 0; d < WT; ++d) Gbd[j][d] = tv[d];
  for (int j = 0; j < NN; ++j)
    for (int d = 0; d < WT; ++d) T.Gb[j][d] = (float)Gbd[j][d];
  // eval-point basis + anchored 12-tap x-filter
  int    s_all[NE] = {};
  double dN[NE][4] = {};
  for (int i = 0; i < NE; ++i) {
    float xe = (float)(-1.0 + (2.0 * i) / 1023.0);
    if (i == 0) xe = -1.0f;
    if (i == NE - 1) xe = 1.0f;
    double u = (double)xe;
    int s = cfindspan(u, t);
    double N[4] = {};
    cdeboor4(u, t, s, N);
    s_all[i] = s;
    for (int k = 0; k < 4; ++k) dN[i][k] = N[k];
    T.espan[i] = s;
    T.ebas[i * 4 + 0] = (float)N[0];
    T.ebas[i * 4 + 1] = (float)N[1];
    T.ebas[i * 4 + 2] = (float)N[2];
    T.ebas[i * 4 + 3] = (float)N[3];
  }
  // W3: out[x] = sum_m W3[x][m] * R[a3 + m], a3 = (s_all[quad0]-3)&~3.
  for (int xx = 0; xx < NE; ++xx) {
    const int a3 = (s_all[(xx >> 2) << 2] - 3) & ~3;
    for (int k = 0; k < 4; ++k) {
      const int m = s_all[xx] - 3 + k - a3;
      T.W3[xx][m] = (float)dN[xx][k];
    }
  }
  return T;
}

__constant__ Tables g_tab = make_tables();

// ------------- K1: full 2D banded solve, register-staged stage 1 -------------
// CoefT[bc][j][i] = sum_{d,e} Gb[i][d]*Gb[j][e]*Z[bc][i-8+d][j-8+e]
// Stage 1 reads Z windows DIRECTLY from global (coalesced 256B groups, 4x
// redundancy served by L1); boundary handling = address clamp + zero taps.
// Only LDS use is the transposed stage-1 result At (22.8 KB) -> 1 barrier.

__global__ __launch_bounds__(256) void k_solve2d(const float* __restrict__ Z,
                                                 float* __restrict__ CT) {
  const int it = blockIdx.x * 64;
  const int jt = blockIdx.y * 64;
  const int bc = blockIdx.z;
  const float* __restrict__ src = Z + (size_t)bc * (NN * NN);
  __shared__ float At[64][89];   // stage-1 result TRANSPOSED: At[jc][ii]
  const int tid = threadIdx.x;
  const int q4 = (tid & 15) * 4;    // quad base (jc for stage1, ic for stage2)

  { // stage 1: 17-tap along j, 80 i-rows, straight from global
    float cy[4][WT];
    #pragma unroll
    for (int q = 0; q < 4; ++q)
      #pragma unroll
      for (int d = 0; d < WT; ++d)
        cy[q][d] = g_tab.Gb[jt + q4 + q][d];
    #pragma unroll 1
    for (int p = 0; p < 5; ++p) {
      const int ii = p * 16 + (tid >> 4);
      int gi = it - 8 + ii;
      gi = (gi < 0) ? 0 : ((gi > NN - 1) ? NN - 1 : gi);   // clamp: garbage killed by stage-2 zero taps
      const float* __restrict__ rowp = &src[(size_t)gi * NN];
      float w[20];
      #pragma unroll
      for (int e = 0; e < 5; ++e) {
        int gj = jt + q4 - 8 + e * 4;                       // 4-aligned granule
        gj = (gj < 0) ? 0 : ((gj > NN - 4) ? NN - 4 : gj);  // clamp: dead granules hit zero taps
        *(float4*)&w[e * 4] = *(const float4*)&rowp[gj];
      }
      float4 a = make_float4(0.f, 0.f, 0.f, 0.f);
      #pragma unroll
      for (int d = 0; d < WT; ++d) {
        a.x += cy[0][d] * w[0 + d];
        a.y += cy[1][d] * w[1 + d];
        a.z += cy[2][d] * w[2 + d];
        a.w += cy[3][d] * w[3 + d];
      }
      At[q4 + 0][ii] = a.x;
      At[q4 + 1][ii] = a.y;
      At[q4 + 2][ii] = a.z;
      At[q4 + 3][ii] = a.w;
    }
  }
  { // stage 2: 17-tap along i; coalesced writes
    float cx[4][WT];
    #pragma unroll
    for (int q = 0; q < 4; ++q)
      #pragma unroll
      for (int d = 0; d < WT; ++d)
        cx[q][d] = g_tab.Gb[it + q4 + q][d];
    __syncthreads();
    float* __restrict__ dst = CT + (size_t)bc * (NN * NN);
    #pragma unroll 1
    for (int p = 0; p < 4; ++p) {
      const int jc = p * 16 + (tid >> 4);
      float w[20];
      #pragma unroll
      for (int e = 0; e < 5; ++e)
        *(float4*)&w[e * 4] = *(const float4*)&At[jc][q4 + e * 4];
      float4 a = make_float4(0.f, 0.f, 0.f, 0.f);
      #pragma unroll
      for (int d = 0; d < WT; ++d) {
        a.x += cx[0][d] * w[0 + d];
        a.y += cx[1][d] * w[1 + d];
        a.z += cx[2][d] * w[2 + d];
        a.w += cx[3][d] * w[3 + d];
      }
      *(float4*)&dst[(size_t)(jt + jc) * NN + it + q4] = a;
    }
  }
}

// ------------- K2: BARRIER-FREE y-tiled eval -------------
// Per block: 16 output rows; 14-row CoefT window loaded once (single barrier).
// Each thread owns one x-quad; per y-pair it privately rebuilds its 12-float
// R window from rows[] (union <= 5 rows, wave-uniform branch), applies the
// anchored 12-tap x-filter, stores 2 float4 NON-TEMPORALLY (write-once stream).

__global__ __launch_bounds__(256) void k_eval6(const float* __restrict__ CT,
                                               float* __restrict__ out) {
  const int ytile = ((blockIdx.x & 7) << 3) | (blockIdx.x >> 3);  // XCD-chunked swizzle (64 tiles)
  const int y0 = ytile * YT;
  const int bc = blockIdx.y;
  const float* __restrict__ S = CT + (size_t)bc * (NN * NN);
  __shared__ float rows[14][524];   // 512 data + 12 zeroed pad (a3+11 <= 519)
  const int tid = threadIdx.x;
  const int rlo = g_tab.espan[y0] - 3;

  // load 14-row window (contiguous 28 KB of CT)
  for (int u = tid; u < 14 * 128; u += 256) {
    const int rr = u >> 7, c4 = (u & 127) * 4;
    const int r = rlo + rr;
    float4 v = (r < NN) ? *(const float4*)&S[(size_t)r * NN + c4]
                        : make_float4(0.f, 0.f, 0.f, 0.f);
    *(float4*)&rows[rr][c4] = v;
  }
  if (tid < 42) {   // zero the pad columns (poison could be NaN; NaN*0 = NaN)
    const int rr = tid / 3, c4 = 512 + (tid % 3) * 4;
    *(float4*)&rows[rr][c4] = make_float4(0.f, 0.f, 0.f, 0.f);
  }

  // hoisted per-thread constants
  const int x0 = tid * 4;
  const int a3 = (g_tab.espan[x0] - 3) & ~3;     // 16B-aligned window base
  float tp[4][12];
  #pragma unroll
  for (int e = 0; e < 4; ++e)
    #pragma unroll
    for (int m = 0; m < 12; ++m)
      tp[e][m] = g_tab.W3[x0 + e][m];

  __syncthreads();

  float* __restrict__ O0 = out + ((size_t)bc * NE + y0) * NE + x0;
  #pragma unroll 1
  for (int k = 0; k < YT / 2; ++k) {
    const int ya = y0 + 2 * k;
    const int ry0 = g_tab.espan[ya] - rlo;       // rows ry0-3..ry0 for ya
    const int ry1 = g_tab.espan[ya + 1] - rlo;   // in {ry0, ry0+1}
    const float4 wy0 = *(const float4*)&g_tab.ebas[ya * 4];
    const float4 wy1 = *(const float4*)&g_tab.ebas[(ya + 1) * 4];
    const int rb = ry0 - 3;                      // 0..8 (always in [0,13])
    float R0[12], R1[12];
    #pragma unroll
    for (int m = 0; m < 12; ++m) { R0[m] = 0.f; R1[m] = 0.f; }
    if (ry1 == ry0) {                            // wave-uniform scalar branch
      #pragma unroll
      for (int kk = 0; kk < 4; ++kk) {
        float wa[12];
        #pragma unroll
        for (int e = 0; e < 3; ++e)
          *(float4*)&wa[e * 4] = *(const float4*)&rows[rb + kk][a3 + e * 4];
        const float w0 = (&wy0.x)[kk], w1 = (&wy1.x)[kk];
        #pragma unroll
        for (int m = 0; m < 12; ++m) { R0[m] += w0 * wa[m]; R1[m] += w1 * wa[m]; }
      }
    } else {                                     // ry1 = ry0+1: union is 5 rows
      #pragma unroll
      for (int kk = 0; kk < 5; ++kk) {
        float wa[12];
        #pragma unroll
        for (int e = 0; e < 3; ++e)
          *(float4*)&wa[e * 4] = *(const float4*)&rows[rb + kk][a3 + e * 4];
        if (kk < 4) {
          const float w0 = (&wy0.x)[kk];
          #pragma unroll
          for (int m = 0; m < 12; ++m) R0[m] += w0 * wa[m];
        }
        if (kk > 0) {
          const float w1 = (&wy1.x)[kk - 1];
          #pragma unroll
          for (int m = 0; m < 12; ++m) R1[m] += w1 * wa[m];
        }
      }
    }
    v4f o0, o1;
    #pragma unroll
    for (int e = 0; e < 4; ++e) {
      float s0 = 0.f, s1 = 0.f;
      #pragma unroll
      for (int m = 0; m < 12; ++m) {
        s0 += tp[e][m] * R0[m];
        s1 += tp[e][m] * R1[m];
      }
      o0[e] = s0;
      o1[e] = s1;
    }
    __builtin_nontemporal_store(o0, (v4f*)&O0[(size_t)(2 * k)     * NE]);
    __builtin_nontemporal_store(o1, (v4f*)&O0[(size_t)(2 * k + 1) * NE]);
  }
}

// ---------------- host launcher ----------------

extern "C" void kernel_launch(void* const* d_in, const int* in_sizes, int n_in,
                              void* d_out, int out_size, void* d_ws, size_t ws_size,
                              hipStream_t stream) {
  (void)in_sizes; (void)n_in; (void)out_size; (void)ws_size;
  const float* Z = (const float*)d_in[0];
  float* out = (float*)d_out;
  float* CT = (float*)d_ws;      // 64 MB (must not alias out)

  k_solve2d<<<dim3(8, 8, NBC),    256, 0, stream>>>(Z,  CT);   // full 2D banded solve
  k_eval6  <<<dim3(NE / YT, NBC), 256, 0, stream>>>(CT, out);  // barrier-free eval
}

// Round 11
// 115.188 us; speedup vs baseline: 1.2614x; 1.0019x over previous
//
#include <hip/hip_runtime.h>

#define NN  512    // data grid / coefficient count per axis
#define NE  1024   // eval points per axis
#define NBC 64     // batch * channels
#define WH  8      // truncated-inverse half width
#define WT  17     // 2*WH+1 taps
#define YT  16     // y-tile per eval block

typedef float v4f __attribute__((ext_vector_type(4)));   // native vec for nontemporal builtins

// ================= compile-time table generation =================
// Mirrors the reference: x = float32 linspace(-1,1,512); knots via float32
// cumsum sliding mean; basis via de Boor in double; banded LU in double;
// truncated inverse band Gb (half-width 8) for BOTH solve directions; and
// W3 = the 4-tap eval basis re-anchored to a per-quad 16B-aligned 12-tap
// window so runtime register indexing is fully static.
// NOTE: Gb rows have EXACT ZEROS at tap positions whose source column falls
// outside [0,NN) — the solve kernel exploits this to replace boundary
// predication with address clamping.

struct Tables {
  float Gb[NN][WT];      // truncated A^-1 band
  int   espan[NE];
  float ebas[NE * 4];    // y-combine weights (float4-aligned)
  float W3[NE][12];      // anchored 4-tap x-filter (zeros elsewhere)
};

constexpr int cfindspan(double u, const float* t) {
  if (u >= (double)t[NN]) return NN - 1;          // t[512] == 1.0
  int lo = 3, hi = NN - 1;
  while (lo < hi) {
    int mid = (lo + hi + 1) >> 1;
    if ((double)t[mid] <= u) lo = mid; else hi = mid - 1;
  }
  return lo;
}

constexpr void cdeboor4(double u, const float* t, int s, double* N) {
  double left[4] = {}, right[4] = {};
  N[0] = 1.0; N[1] = 0.0; N[2] = 0.0; N[3] = 0.0;
  for (int d = 1; d <= 3; ++d) {
    left[d]  = u - (double)t[s + 1 - d];
    right[d] = (double)t[s + d] - u;
    double saved = 0.0;
    for (int r = 0; r < d; ++r) {
      double temp = N[r] / (right[r + 1] + left[d - r]);
      N[r] = saved + right[r + 1] * temp;
      saved = left[d - r] * temp;
    }
    N[d] = saved;
  }
}

constexpr Tables make_tables() {
  Tables T{};
  float x[NN] = {};
  for (int i = 0; i < NN; ++i) x[i] = (float)(-1.0 + (2.0 * i) / 511.0);
  x[0] = -1.0f; x[NN - 1] = 1.0f;
  float t[NN + 4] = {};
  {
    float cs[NN + 1] = {};
    for (int i = 0; i < NN; ++i) cs[i + 1] = cs[i] + x[i];
    for (int i = 0; i < NN - 4; ++i) t[4 + i] = (cs[4 + i] - cs[1 + i]) / 3.0f;
    for (int i = 0; i < 4; ++i) { t[i] = -1.0f; t[NN + i] = 1.0f; }
  }
  double W[NN][7] = {};
  for (int r = 0; r < NN; ++r) {
    double u = (double)x[r];
    int s = cfindspan(u, t);
    double N[4] = {};
    cdeboor4(u, t, s, N);
    for (int dd = 0; dd < 4; ++dd) W[r][s - r + dd] += N[dd];
  }
  for (int r = 0; r < NN; ++r) {
    double rd = 1.0 / W[r][3];
    for (int k = 1; k <= 3; ++k) {
      if (r + k < NN) {
        double l = W[r + k][3 - k] * rd;
        W[r + k][3 - k] = l;
        for (int cc = 1; cc <= 3; ++cc) W[r + k][3 - k + cc] -= l * W[r][3 + cc];
      }
    }
  }
  // truncated inverse band
  double Gbd[NN][WT] = {};
  double tv[WT] = {};
  for (int pass = 0; pass < 3; ++pass) {
    const int ylo = (pass == 0) ? 0 : (pass == 1) ? 480 : 256;
    const int yhi = (pass == 0) ? 32 : (pass == 1) ? 512 : 257;
    for (int y = ylo; y < yhi; ++y) {
      double wv[21] = {};
      int rend = y + 20; if (rend > NN - 1) rend = NN - 1;
      wv[0] = 1.0;
      for (int r = y + 1; r <= rend; ++r) {
        double acc = 0.0;
        if (r - 1 >= y) acc += W[r][2] * wv[r - 1 - y];
        if (r - 2 >= y) acc += W[r][1] * wv[r - 2 - y];
        if (r - 3 >= y) acc += W[r][0] * wv[r - 3 - y];
        wv[r - y] = -acc;
      }
      double g[29] = {};
      int glo = y - WH; if (glo < 0) glo = 0;
      for (int r = rend; r >= glo; --r) {
        double acc = (r >= y) ? wv[r - y] : 0.0;
        if (r + 1 <= rend) acc -= W[r][4] * g[r + 1 - (y - WH)];
        if (r + 2 <= rend) acc -= W[r][5] * g[r + 2 - (y - WH)];
        if (r + 3 <= rend) acc -= W[r][6] * g[r + 3 - (y - WH)];
        g[r - (y - WH)] = acc / W[r][3];
      }
      if (pass == 2) {
        for (int d = 0; d < WT; ++d) tv[d] = g[16 - d];
      } else {
        int jlo = y - WH; if (jlo < 0) jlo = 0;
        int jhi = y + WH; if (jhi > NN - 1) jhi = NN - 1;
        for (int j = jlo; j <= jhi; ++j) {
          const bool bdry = (pass == 0) ? (j < 24) : (j >= 488);
          if (bdry) Gbd[j][y - j + WH] = g[j - (y - WH)];
        }
      }
    }
  }
  for (int j = 24; j < 488; ++j)
    for (int d = 0; d < WT; ++d) Gbd[j][d] = tv[d];
  for (int j = 0; j < NN; ++j)
    for (int d = 0; d < WT; ++d) T.Gb[j][d] = (float)Gbd[j][d];
  // eval-point basis + anchored 12-tap x-filter
  int    s_all[NE] = {};
  double dN[NE][4] = {};
  for (int i = 0; i < NE; ++i) {
    float xe = (float)(-1.0 + (2.0 * i) / 1023.0);
    if (i == 0) xe = -1.0f;
    if (i == NE - 1) xe = 1.0f;
    double u = (double)xe;
    int s = cfindspan(u, t);
    double N[4] = {};
    cdeboor4(u, t, s, N);
    s_all[i] = s;
    for (int k = 0; k < 4; ++k) dN[i][k] = N[k];
    T.espan[i] = s;
    T.ebas[i * 4 + 0] = (float)N[0];
    T.ebas[i * 4 + 1] = (float)N[1];
    T.ebas[i * 4 + 2] = (float)N[2];
    T.ebas[i * 4 + 3] = (float)N[3];
  }
  // W3: out[x] = sum_m W3[x][m] * R[a3 + m], a3 = (s_all[quad0]-3)&~3.
  for (int xx = 0; xx < NE; ++xx) {
    const int a3 = (s_all[(xx >> 2) << 2] - 3) & ~3;
    for (int k = 0; k < 4; ++k) {
      const int m = s_all[xx] - 3 + k - a3;
      T.W3[xx][m] = (float)dN[xx][k];
    }
  }
  return T;
}

__constant__ Tables g_tab = make_tables();

// ------------- K1: full 2D banded solve, register-staged stage 1 -------------
// CoefT[bc][j][i] = sum_{d,e} Gb[i][d]*Gb[j][e]*Z[bc][i-8+d][j-8+e]
// Stage 1 reads Z windows DIRECTLY from global (coalesced 256B groups, 4x
// redundancy served by L1); boundary handling = address clamp + zero taps.
// Only LDS use is the transposed stage-1 result At (22.8 KB) -> 1 barrier.

__global__ __launch_bounds__(256) void k_solve2d(const float* __restrict__ Z,
                                                 float* __restrict__ CT) {
  const int it = blockIdx.x * 64;
  const int jt = blockIdx.y * 64;
  const int bc = blockIdx.z;
  const float* __restrict__ src = Z + (size_t)bc * (NN * NN);
  __shared__ float At[64][89];   // stage-1 result TRANSPOSED: At[jc][ii]
  const int tid = threadIdx.x;
  const int q4 = (tid & 15) * 4;    // quad base (jc for stage1, ic for stage2)

  { // stage 1: 17-tap along j, 80 i-rows, straight from global
    float cy[4][WT];
    #pragma unroll
    for (int q = 0; q < 4; ++q)
      #pragma unroll
      for (int d = 0; d < WT; ++d)
        cy[q][d] = g_tab.Gb[jt + q4 + q][d];
    #pragma unroll 1
    for (int p = 0; p < 5; ++p) {
      const int ii = p * 16 + (tid >> 4);
      int gi = it - 8 + ii;
      gi = (gi < 0) ? 0 : ((gi > NN - 1) ? NN - 1 : gi);   // clamp: garbage killed by stage-2 zero taps
      const float* __restrict__ rowp = &src[(size_t)gi * NN];
      float w[20];
      #pragma unroll
      for (int e = 0; e < 5; ++e) {
        int gj = jt + q4 - 8 + e * 4;                       // 4-aligned granule
        gj = (gj < 0) ? 0 : ((gj > NN - 4) ? NN - 4 : gj);  // clamp: dead granules hit zero taps
        *(float4*)&w[e * 4] = *(const float4*)&rowp[gj];
      }
      float4 a = make_float4(0.f, 0.f, 0.f, 0.f);
      #pragma unroll
      for (int d = 0; d < WT; ++d) {
        a.x += cy[0][d] * w[0 + d];
        a.y += cy[1][d] * w[1 + d];
        a.z += cy[2][d] * w[2 + d];
        a.w += cy[3][d] * w[3 + d];
      }
      At[q4 + 0][ii] = a.x;
      At[q4 + 1][ii] = a.y;
      At[q4 + 2][ii] = a.z;
      At[q4 + 3][ii] = a.w;
    }
  }
  { // stage 2: 17-tap along i; coalesced writes
    float cx[4][WT];
    #pragma unroll
    for (int q = 0; q < 4; ++q)
      #pragma unroll
      for (int d = 0; d < WT; ++d)
        cx[q][d] = g_tab.Gb[it + q4 + q][d];
    __syncthreads();
    float* __restrict__ dst = CT + (size_t)bc * (NN * NN);
    #pragma unroll 1
    for (int p = 0; p < 4; ++p) {
      const int jc = p * 16 + (tid >> 4);
      float w[20];
      #pragma unroll
      for (int e = 0; e < 5; ++e)
        *(float4*)&w[e * 4] = *(const float4*)&At[jc][q4 + e * 4];
      float4 a = make_float4(0.f, 0.f, 0.f, 0.f);
      #pragma unroll
      for (int d = 0; d < WT; ++d) {
        a.x += cx[0][d] * w[0 + d];
        a.y += cx[1][d] * w[1 + d];
        a.z += cx[2][d] * w[2 + d];
        a.w += cx[3][d] * w[3 + d];
      }
      *(float4*)&dst[(size_t)(jt + jc) * NN + it + q4] = a;
    }
  }
}

// ------------- K2: sliding P-window eval -------------
// P[r] = anchored 12-tap x-filter of CT row r at this thread's x-quad
// (computed ONCE per unique row: 3 ds_read_b128 + 48 FMA). out[y] =
// 4-tap y-combine of the current 4-row P window (16 FMA + 1 nt store).
// Window slides by 0/1 per y (eval step < knot spacing) via a wave-uniform
// branch with fully static register indexing. Barrier-free steady state.

__global__ __launch_bounds__(256) void k_eval7(const float* __restrict__ CT,
                                               float* __restrict__ out) {
  const int ytile = ((blockIdx.x & 7) << 3) | (blockIdx.x >> 3);  // XCD-chunked swizzle (64 tiles)
  const int y0 = ytile * YT;
  const int bc = blockIdx.y;
  const float* __restrict__ S = CT + (size_t)bc * (NN * NN);
  __shared__ float rows[14][524];   // 512 data + 12 zeroed pad (a3+11 <= 523)
  const int tid = threadIdx.x;
  const int rlo = g_tab.espan[y0] - 3;

  // load 14-row window (contiguous 28 KB of CT)
  for (int u = tid; u < 14 * 128; u += 256) {
    const int rr = u >> 7, c4 = (u & 127) * 4;
    const int r = rlo + rr;
    float4 v = (r < NN) ? *(const float4*)&S[(size_t)r * NN + c4]
                        : make_float4(0.f, 0.f, 0.f, 0.f);
    *(float4*)&rows[rr][c4] = v;
  }
  if (tid < 42) {   // zero the pad columns (poison could be NaN; NaN*0 = NaN)
    const int rr = tid / 3, c4 = 512 + (tid % 3) * 4;
    *(float4*)&rows[rr][c4] = make_float4(0.f, 0.f, 0.f, 0.f);
  }

  // hoisted per-thread constants
  const int x0 = tid * 4;
  const int a3 = (g_tab.espan[x0] - 3) & ~3;     // 16B-aligned window base
  float tp[4][12];
  #pragma unroll
  for (int e = 0; e < 4; ++e)
    #pragma unroll
    for (int m = 0; m < 12; ++m)
      tp[e][m] = g_tab.W3[x0 + e][m];

  __syncthreads();

  // filtered quad of LDS row r (static unrolled 12-tap dot per element)
  auto filterP = [&](int r) -> v4f {
    float w[12];
    #pragma unroll
    for (int e = 0; e < 3; ++e)
      *(float4*)&w[e * 4] = *(const float4*)&rows[r][a3 + e * 4];
    v4f p;
    #pragma unroll
    for (int e = 0; e < 4; ++e) {
      float s0 = 0.f, s1 = 0.f;
      #pragma unroll
      for (int m = 0; m < 12; m += 2) {
        s0 += tp[e][m]     * w[m];
        s1 += tp[e][m + 1] * w[m + 1];
      }
      p[e] = s0 + s1;
    }
    return p;
  };

  // initial window: ry(y0) = 3 -> rows 0..3
  v4f P0 = filterP(0), P1 = filterP(1), P2 = filterP(2), P3 = filterP(3);
  int prev = 3;
  float* __restrict__ O0 = out + ((size_t)bc * NE + y0) * NE + x0;
  #pragma unroll 1
  for (int k = 0; k < YT; ++k) {
    const int ry = g_tab.espan[y0 + k] - rlo;    // wave-uniform; advances 0 or 1
    if (ry != prev) {                            // slide window (static moves)
      P0 = P1; P1 = P2; P2 = P3;
      P3 = filterP(ry);
      prev = ry;
    }
    const float4 wy = *(const float4*)&g_tab.ebas[(y0 + k) * 4];
    v4f o;
    #pragma unroll
    for (int e = 0; e < 4; ++e)
      o[e] = wy.x * P0[e] + wy.y * P1[e] + wy.z * P2[e] + wy.w * P3[e];
    __builtin_nontemporal_store(o, (v4f*)&O0[(size_t)k * NE]);
  }
}

// ---------------- host launcher ----------------

extern "C" void kernel_launch(void* const* d_in, const int* in_sizes, int n_in,
                              void* d_out, int out_size, void* d_ws, size_t ws_size,
                              hipStream_t stream) {
  (void)in_sizes; (void)n_in; (void)out_size; (void)ws_size;
  const float* Z = (const float*)d_in[0];
  float* out = (float*)d_out;
  float* CT = (float*)d_ws;      // 64 MB (must not alias out)

  k_solve2d<<<dim3(8, 8, NBC),    256, 0, stream>>>(Z,  CT);   // full 2D banded solve
  k_eval7  <<<dim3(NE / YT, NBC), 256, 0, stream>>>(CT, out);  // sliding P-window eval
}

// Round 12
// 113.096 us; speedup vs baseline: 1.2847x; 1.0185x over previous
//
#include <hip/hip_runtime.h>
#include <hip/hip_bf16.h>

#define NN  512    // data grid / coefficient count per axis
#define NE  1024   // eval points per axis
#define NBC 64     // batch * channels
#define WH  8      // truncated-inverse half width
#define WT  17     // 2*WH+1 taps
#define YT  32     // y-tile per eval block
#define NR  20     // CT row window per eval block (espan drift over 31 steps <= 16)

typedef float v4f __attribute__((ext_vector_type(4)));   // native vec for nontemporal builtins

// ================= compile-time table generation =================
// Mirrors the reference: x = float32 linspace(-1,1,512); knots via float32
// cumsum sliding mean; basis via de Boor in double; banded LU in double;
// truncated inverse band Gb (half-width 8) for BOTH solve directions; and
// W3 = the 4-tap eval basis re-anchored to a per-quad 16B-aligned 12-tap
// window so runtime register indexing is fully static.
// NOTE: Gb rows have EXACT ZEROS at tap positions whose source column falls
// outside [0,NN) — the solve kernel exploits this to replace boundary
// predication with address clamping.

struct Tables {
  float Gb[NN][WT];      // truncated A^-1 band
  int   espan[NE];
  float ebas[NE * 4];    // y-combine weights (float4-aligned)
  float W3[NE][12];      // anchored 4-tap x-filter (zeros elsewhere)
};

constexpr int cfindspan(double u, const float* t) {
  if (u >= (double)t[NN]) return NN - 1;          // t[512] == 1.0
  int lo = 3, hi = NN - 1;
  while (lo < hi) {
    int mid = (lo + hi + 1) >> 1;
    if ((double)t[mid] <= u) lo = mid; else hi = mid - 1;
  }
  return lo;
}

constexpr void cdeboor4(double u, const float* t, int s, double* N) {
  double left[4] = {}, right[4] = {};
  N[0] = 1.0; N[1] = 0.0; N[2] = 0.0; N[3] = 0.0;
  for (int d = 1; d <= 3; ++d) {
    left[d]  = u - (double)t[s + 1 - d];
    right[d] = (double)t[s + d] - u;
    double saved = 0.0;
    for (int r = 0; r < d; ++r) {
      double temp = N[r] / (right[r + 1] + left[d - r]);
      N[r] = saved + right[r + 1] * temp;
      saved = left[d - r] * temp;
    }
    N[d] = saved;
  }
}

constexpr Tables make_tables() {
  Tables T{};
  float x[NN] = {};
  for (int i = 0; i < NN; ++i) x[i] = (float)(-1.0 + (2.0 * i) / 511.0);
  x[0] = -1.0f; x[NN - 1] = 1.0f;
  float t[NN + 4] = {};
  {
    float cs[NN + 1] = {};
    for (int i = 0; i < NN; ++i) cs[i + 1] = cs[i] + x[i];
    for (int i = 0; i < NN - 4; ++i) t[4 + i] = (cs[4 + i] - cs[1 + i]) / 3.0f;
    for (int i = 0; i < 4; ++i) { t[i] = -1.0f; t[NN + i] = 1.0f; }
  }
  double W[NN][7] = {};
  for (int r = 0; r < NN; ++r) {
    double u = (double)x[r];
    int s = cfindspan(u, t);
    double N[4] = {};
    cdeboor4(u, t, s, N);
    for (int dd = 0; dd < 4; ++dd) W[r][s - r + dd] += N[dd];
  }
  for (int r = 0; r < NN; ++r) {
    double rd = 1.0 / W[r][3];
    for (int k = 1; k <= 3; ++k) {
      if (r + k < NN) {
        double l = W[r + k][3 - k] * rd;
        W[r + k][3 - k] = l;
        for (int cc = 1; cc <= 3; ++cc) W[r + k][3 - k + cc] -= l * W[r][3 + cc];
      }
    }
  }
  // truncated inverse band
  double Gbd[NN][WT] = {};
  double tv[WT] = {};
  for (int pass = 0; pass < 3; ++pass) {
    const int ylo = (pass == 0) ? 0 : (pass == 1) ? 480 : 256;
    const int yhi = (pass == 0) ? 32 : (pass == 1) ? 512 : 257;
    for (int y = ylo; y < yhi; ++y) {
      double wv[21] = {};
      int rend = y + 20; if (rend > NN - 1) rend = NN - 1;
      wv[0] = 1.0;
      for (int r = y + 1; r <= rend; ++r) {
        double acc = 0.0;
        if (r - 1 >= y) acc += W[r][2] * wv[r - 1 - y];
        if (r - 2 >= y) acc += W[r][1] * wv[r - 2 - y];
        if (r - 3 >= y) acc += W[r][0] * wv[r - 3 - y];
        wv[r - y] = -acc;
      }
      double g[29] = {};
      int glo = y - WH; if (glo < 0) glo = 0;
      for (int r = rend; r >= glo; --r) {
        double acc = (r >= y) ? wv[r - y] : 0.0;
        if (r + 1 <= rend) acc -= W[r][4] * g[r + 1 - (y - WH)];
        if (r + 2 <= rend) acc -= W[r][5] * g[r + 2 - (y - WH)];
        if (r + 3 <= rend) acc -= W[r][6] * g[r + 3 - (y - WH)];
        g[r - (y - WH)] = acc / W[r][3];
      }
      if (pass == 2) {
        for (int d = 0; d < WT; ++d) tv[d] = g[16 - d];
      } else {
        int jlo = y - WH; if (jlo < 0) jlo = 0;
        int jhi = y + WH; if (jhi > NN - 1) jhi = NN - 1;
        for (int j = jlo; j <= jhi; ++j) {
          const bool bdry = (pass == 0) ? (j < 24) : (j >= 488);
          if (bdry) Gbd[j][y - j + WH] = g[j - (y - WH)];
        }
      }
    }
  }
  for (int j = 24; j < 488; ++j)
    for (int d = 0; d < WT; ++d) Gbd[j][d] = tv[d];
  for (int j = 0; j < NN; ++j)
    for (int d = 0; d < WT; ++d) T.Gb[j][d] = (float)Gbd[j][d];
  // eval-point basis + anchored 12-tap x-filter
  int    s_all[NE] = {};
  double dN[NE][4] = {};
  for (int i = 0; i < NE; ++i) {
    float xe = (float)(-1.0 + (2.0 * i) / 1023.0);
    if (i == 0) xe = -1.0f;
    if (i == NE - 1) xe = 1.0f;
    double u = (double)xe;
    int s = cfindspan(u, t);
    double N[4] = {};
    cdeboor4(u, t, s, N);
    s_all[i] = s;
    for (int k = 0; k < 4; ++k) dN[i][k] = N[k];
    T.espan[i] = s;
    T.ebas[i * 4 + 0] = (float)N[0];
    T.ebas[i * 4 + 1] = (float)N[1];
    T.ebas[i * 4 + 2] = (float)N[2];
    T.ebas[i * 4 + 3] = (float)N[3];
  }
  // W3: out[x] = sum_m W3[x][m] * R[a3 + m], a3 = (s_all[quad0]-3)&~3.
  for (int xx = 0; xx < NE; ++xx) {
    const int a3 = (s_all[(xx >> 2) << 2] - 3) & ~3;
    for (int k = 0; k < 4; ++k) {
      const int m = s_all[xx] - 3 + k - a3;
      T.W3[xx][m] = (float)dN[xx][k];
    }
  }
  return T;
}

__constant__ Tables g_tab = make_tables();

__device__ __forceinline__ unsigned short f2bf(float f) {
  __hip_bfloat16 h = __float2bfloat16(f);              // round-to-nearest-even
  return reinterpret_cast<const unsigned short&>(h);
}

// ------------- K1: full 2D banded solve, register-staged stage 1 -------------
// CT[bc][j][i] (BF16) = sum_{d,e} Gb[i][d]*Gb[j][e]*Z[bc][i-8+d][j-8+e]
// Stage 1 reads Z windows DIRECTLY from global (coalesced 256B groups, 4x
// redundancy served by L1); boundary handling = address clamp + zero taps.
// Only LDS use is the transposed stage-1 result At (22.8 KB) -> 1 barrier.

__global__ __launch_bounds__(256) void k_solve2d(const float* __restrict__ Z,
                                                 unsigned short* __restrict__ CT) {
  const int it = blockIdx.x * 64;
  const int jt = blockIdx.y * 64;
  const int bc = blockIdx.z;
  const float* __restrict__ src = Z + (size_t)bc * (NN * NN);
  __shared__ float At[64][89];   // stage-1 result TRANSPOSED: At[jc][ii]
  const int tid = threadIdx.x;
  const int q4 = (tid & 15) * 4;    // quad base (jc for stage1, ic for stage2)

  { // stage 1: 17-tap along j, 80 i-rows, straight from global
    float cy[4][WT];
    #pragma unroll
    for (int q = 0; q < 4; ++q)
      #pragma unroll
      for (int d = 0; d < WT; ++d)
        cy[q][d] = g_tab.Gb[jt + q4 + q][d];
    #pragma unroll 1
    for (int p = 0; p < 5; ++p) {
      const int ii = p * 16 + (tid >> 4);
      int gi = it - 8 + ii;
      gi = (gi < 0) ? 0 : ((gi > NN - 1) ? NN - 1 : gi);   // clamp: garbage killed by stage-2 zero taps
      const float* __restrict__ rowp = &src[(size_t)gi * NN];
      float w[20];
      #pragma unroll
      for (int e = 0; e < 5; ++e) {
        int gj = jt + q4 - 8 + e * 4;                       // 4-aligned granule
        gj = (gj < 0) ? 0 : ((gj > NN - 4) ? NN - 4 : gj);  // clamp: dead granules hit zero taps
        *(float4*)&w[e * 4] = *(const float4*)&rowp[gj];
      }
      float4 a = make_float4(0.f, 0.f, 0.f, 0.f);
      #pragma unroll
      for (int d = 0; d < WT; ++d) {
        a.x += cy[0][d] * w[0 + d];
        a.y += cy[1][d] * w[1 + d];
        a.z += cy[2][d] * w[2 + d];
        a.w += cy[3][d] * w[3 + d];
      }
      At[q4 + 0][ii] = a.x;
      At[q4 + 1][ii] = a.y;
      At[q4 + 2][ii] = a.z;
      At[q4 + 3][ii] = a.w;
    }
  }
  { // stage 2: 17-tap along i; coalesced bf16 writes
    float cx[4][WT];
    #pragma unroll
    for (int q = 0; q < 4; ++q)
      #pragma unroll
      for (int d = 0; d < WT; ++d)
        cx[q][d] = g_tab.Gb[it + q4 + q][d];
    __syncthreads();
    unsigned short* __restrict__ dst = CT + (size_t)bc * (NN * NN);
    #pragma unroll 1
    for (int p = 0; p < 4; ++p) {
      const int jc = p * 16 + (tid >> 4);
      float w[20];
      #pragma unroll
      for (int e = 0; e < 5; ++e)
        *(float4*)&w[e * 4] = *(const float4*)&At[jc][q4 + e * 4];
      float4 a = make_float4(0.f, 0.f, 0.f, 0.f);
      #pragma unroll
      for (int d = 0; d < WT; ++d) {
        a.x += cx[0][d] * w[0 + d];
        a.y += cx[1][d] * w[1 + d];
        a.z += cx[2][d] * w[2 + d];
        a.w += cx[3][d] * w[3 + d];
      }
      ushort4 o;
      o.x = f2bf(a.x); o.y = f2bf(a.y); o.z = f2bf(a.z); o.w = f2bf(a.w);
      *(ushort4*)&dst[(size_t)(jt + jc) * NN + it + q4] = o;   // 8B aligned
    }
  }
}

// ------------- K2: sliding P-window eval (bf16 CT, YT=32) -------------
// P[r] = anchored 12-tap x-filter of CT row r at this thread's x-quad
// (3 ds_read_b64 + 12 unpack + 48 FMA, once per unique row). out[y] =
// 4-tap y-combine of the 4-row P window + 1 nontemporal float4 store.
// Window slides 0/1 per y via wave-uniform branch, static indexing.

__global__ __launch_bounds__(256) void k_eval8(const unsigned short* __restrict__ CT,
                                               float* __restrict__ out) {
  const int b = blockIdx.x;                         // 32 y-tiles
  const int ytile = ((b & 7) << 2) | (b >> 3);      // XCD-chunked swizzle (bijective, 32)
  const int y0 = ytile * YT;
  const int bc = blockIdx.y;
  const unsigned short* __restrict__ S = CT + (size_t)bc * (NN * NN);
  __shared__ unsigned short rows[NR][528];          // 512 data + 16 zero pad (a3+11 <= 519)
  const int tid = threadIdx.x;
  const int rlo = g_tab.espan[y0] - 3;

  // load NR-row window (bf16, uint4 = 8 coefs per load)
  for (int u = tid; u < NR * 66; u += 256) {
    const int rr = u / 66, c8 = (u % 66) * 8;
    const int r = rlo + rr;
    uint4 v = make_uint4(0u, 0u, 0u, 0u);
    if (r < NN && c8 < 512) v = *(const uint4*)&S[(size_t)r * NN + c8];
    *(uint4*)&rows[rr][c8] = v;
  }

  // hoisted per-thread constants
  const int x0 = tid * 4;
  const int a3 = (g_tab.espan[x0] - 3) & ~3;        // window base (mult of 4)
  float tp[4][12];
  #pragma unroll
  for (int e = 0; e < 4; ++e)
    #pragma unroll
    for (int m = 0; m < 12; ++m)
      tp[e][m] = g_tab.W3[x0 + e][m];

  __syncthreads();

  // filtered quad of bf16 LDS row r
  auto filterP = [&](int r) -> v4f {
    uint2 q0 = *(const uint2*)&rows[r][a3];          // 8B aligned (a3 mult 4)
    uint2 q1 = *(const uint2*)&rows[r][a3 + 4];
    uint2 q2 = *(const uint2*)&rows[r][a3 + 8];
    float w[12];
    w[0]  = __uint_as_float(q0.x << 16); w[1]  = __uint_as_float(q0.x & 0xffff0000u);
    w[2]  = __uint_as_float(q0.y << 16); w[3]  = __uint_as_float(q0.y & 0xffff0000u);
    w[4]  = __uint_as_float(q1.x << 16); w[5]  = __uint_as_float(q1.x & 0xffff0000u);
    w[6]  = __uint_as_float(q1.y << 16); w[7]  = __uint_as_float(q1.y & 0xffff0000u);
    w[8]  = __uint_as_float(q2.x << 16); w[9]  = __uint_as_float(q2.x & 0xffff0000u);
    w[10] = __uint_as_float(q2.y << 16); w[11] = __uint_as_float(q2.y & 0xffff0000u);
    v4f p;
    #pragma unroll
    for (int e = 0; e < 4; ++e) {
      float s0 = 0.f, s1 = 0.f;
      #pragma unroll
      for (int m = 0; m < 12; m += 2) {
        s0 += tp[e][m]     * w[m];
        s1 += tp[e][m + 1] * w[m + 1];
      }
      p[e] = s0 + s1;
    }
    return p;
  };

  // initial window: ry(y0) = 3 -> rows 0..3
  v4f P0 = filterP(0), P1 = filterP(1), P2 = filterP(2), P3 = filterP(3);
  int prev = 3;
  float* __restrict__ O0 = out + ((size_t)bc * NE + y0) * NE + x0;
  #pragma unroll 1
  for (int k = 0; k < YT; ++k) {
    const int ry = g_tab.espan[y0 + k] - rlo;       // wave-uniform; advances 0 or 1
    if (ry != prev) {                               // slide window (static moves)
      P0 = P1; P1 = P2; P2 = P3;
      P3 = filterP(ry);
      prev = ry;
    }
    const float4 wy = *(const float4*)&g_tab.ebas[(y0 + k) * 4];
    v4f o;
    #pragma unroll
    for (int e = 0; e < 4; ++e)
      o[e] = wy.x * P0[e] + wy.y * P1[e] + wy.z * P2[e] + wy.w * P3[e];
    __builtin_nontemporal_store(o, (v4f*)&O0[(size_t)k * NE]);
  }
}

// ---------------- host launcher ----------------

extern "C" void kernel_launch(void* const* d_in, const int* in_sizes, int n_in,
                              void* d_out, int out_size, void* d_ws, size_t ws_size,
                              hipStream_t stream) {
  (void)in_sizes; (void)n_in; (void)out_size; (void)ws_size;
  const float* Z = (const float*)d_in[0];
  float* out = (float*)d_out;
  unsigned short* CT = (unsigned short*)d_ws;   // 32 MB bf16 coefficients

  k_solve2d<<<dim3(8, 8, NBC),   256, 0, stream>>>(Z,  CT);   // 2D banded solve -> bf16 CT
  k_eval8  <<<dim3(NE / YT, NBC), 256, 0, stream>>>(CT, out); // sliding P-window eval
}

// Round 13
// 109.952 us; speedup vs baseline: 1.3215x; 1.0286x over previous
//
#include <hip/hip_runtime.h>
#include <hip/hip_bf16.h>

#define NN  512    // data grid / coefficient count per axis
#define NE  1024   // eval points per axis
#define NBC 64     // batch * channels
#define WH  6      // truncated-inverse half width (0.268^7 ~ 1e-4 rel err)
#define WT  13     // 2*WH+1 taps
#define YT  32     // y-tile per eval block
#define NR  20     // CT row window per eval block (espan drift over 31 steps <= 16)

typedef float v4f __attribute__((ext_vector_type(4)));

// ================= compile-time table generation =================
// Mirrors the reference: x = float32 linspace(-1,1,512); knots via float32
// cumsum sliding mean; basis via de Boor in double; banded LU in double;
// truncated inverse band Gb (half-width 6) for BOTH solve directions; and
// W3 = the 4-tap eval basis re-anchored to a per-quad 16B-aligned 12-tap
// window so runtime register indexing is fully static.
// NOTE: Gb rows have EXACT ZEROS at tap positions whose source column falls
// outside [0,NN) — the solve kernel exploits this to replace boundary
// predication with address clamping.

struct Tables {
  float Gb[NN][WT];      // truncated A^-1 band
  int   espan[NE];
  float ebas[NE * 4];    // y-combine weights (float4-aligned)
  float W3[NE][12];      // anchored 4-tap x-filter (zeros elsewhere)
};

constexpr int cfindspan(double u, const float* t) {
  if (u >= (double)t[NN]) return NN - 1;          // t[512] == 1.0
  int lo = 3, hi = NN - 1;
  while (lo < hi) {
    int mid = (lo + hi + 1) >> 1;
    if ((double)t[mid] <= u) lo = mid; else hi = mid - 1;
  }
  return lo;
}

constexpr void cdeboor4(double u, const float* t, int s, double* N) {
  double left[4] = {}, right[4] = {};
  N[0] = 1.0; N[1] = 0.0; N[2] = 0.0; N[3] = 0.0;
  for (int d = 1; d <= 3; ++d) {
    left[d]  = u - (double)t[s + 1 - d];
    right[d] = (double)t[s + d] - u;
    double saved = 0.0;
    for (int r = 0; r < d; ++r) {
      double temp = N[r] / (right[r + 1] + left[d - r]);
      N[r] = saved + right[r + 1] * temp;
      saved = left[d - r] * temp;
    }
    N[d] = saved;
  }
}

constexpr Tables make_tables() {
  Tables T{};
  float x[NN] = {};
  for (int i = 0; i < NN; ++i) x[i] = (float)(-1.0 + (2.0 * i) / 511.0);
  x[0] = -1.0f; x[NN - 1] = 1.0f;
  float t[NN + 4] = {};
  {
    float cs[NN + 1] = {};
    for (int i = 0; i < NN; ++i) cs[i + 1] = cs[i] + x[i];
    for (int i = 0; i < NN - 4; ++i) t[4 + i] = (cs[4 + i] - cs[1 + i]) / 3.0f;
    for (int i = 0; i < 4; ++i) { t[i] = -1.0f; t[NN + i] = 1.0f; }
  }
  double W[NN][7] = {};
  for (int r = 0; r < NN; ++r) {
    double u = (double)x[r];
    int s = cfindspan(u, t);
    double N[4] = {};
    cdeboor4(u, t, s, N);
    for (int dd = 0; dd < 4; ++dd) W[r][s - r + dd] += N[dd];
  }
  for (int r = 0; r < NN; ++r) {
    double rd = 1.0 / W[r][3];
    for (int k = 1; k <= 3; ++k) {
      if (r + k < NN) {
        double l = W[r + k][3 - k] * rd;
        W[r + k][3 - k] = l;
        for (int cc = 1; cc <= 3; ++cc) W[r + k][3 - k + cc] -= l * W[r][3 + cc];
      }
    }
  }
  // truncated inverse band (half-width WH)
  double Gbd[NN][WT] = {};
  double tv[WT] = {};
  for (int pass = 0; pass < 3; ++pass) {
    const int ylo = (pass == 0) ? 0 : (pass == 1) ? 480 : 256;
    const int yhi = (pass == 0) ? 32 : (pass == 1) ? 512 : 257;
    for (int y = ylo; y < yhi; ++y) {
      double wv[21] = {};
      int rend = y + 20; if (rend > NN - 1) rend = NN - 1;
      wv[0] = 1.0;
      for (int r = y + 1; r <= rend; ++r) {
        double acc = 0.0;
        if (r - 1 >= y) acc += W[r][2] * wv[r - 1 - y];
        if (r - 2 >= y) acc += W[r][1] * wv[r - 2 - y];
        if (r - 3 >= y) acc += W[r][0] * wv[r - 3 - y];
        wv[r - y] = -acc;
      }
      double g[33] = {};
      int glo = y - WH; if (glo < 0) glo = 0;
      for (int r = rend; r >= glo; --r) {
        double acc = (r >= y) ? wv[r - y] : 0.0;
        if (r + 1 <= rend) acc -= W[r][4] * g[r + 1 - (y - WH)];
        if (r + 2 <= rend) acc -= W[r][5] * g[r + 2 - (y - WH)];
        if (r + 3 <= rend) acc -= W[r][6] * g[r + 3 - (y - WH)];
        g[r - (y - WH)] = acc / W[r][3];
      }
      if (pass == 2) {
        for (int d = 0; d < WT; ++d) tv[d] = g[2 * WH - d];   // Ainv[256+WH-d][256]
      } else {
        int jlo = y - WH; if (jlo < 0) jlo = 0;
        int jhi = y + WH; if (jhi > NN - 1) jhi = NN - 1;
        for (int j = jlo; j <= jhi; ++j) {
          const bool bdry = (pass == 0) ? (j < 24) : (j >= 488);
          if (bdry) Gbd[j][y - j + WH] = g[j - (y - WH)];
        }
      }
    }
  }
  for (int j = 24; j < 488; ++j)
    for (int d = 0; d < WT; ++d) Gbd[j][d] = tv[d];
  for (int j = 0; j < NN; ++j)
    for (int d = 0; d < WT; ++d) T.Gb[j][d] = (float)Gbd[j][d];
  // eval-point basis + anchored 12-tap x-filter
  int    s_all[NE] = {};
  double dN[NE][4] = {};
  for (int i = 0; i < NE; ++i) {
    float xe = (float)(-1.0 + (2.0 * i) / 1023.0);
    if (i == 0) xe = -1.0f;
    if (i == NE - 1) xe = 1.0f;
    double u = (double)xe;
    int s = cfindspan(u, t);
    double N[4] = {};
    cdeboor4(u, t, s, N);
    s_all[i] = s;
    for (int k = 0; k < 4; ++k) dN[i][k] = N[k];
    T.espan[i] = s;
    T.ebas[i * 4 + 0] = (float)N[0];
    T.ebas[i * 4 + 1] = (float)N[1];
    T.ebas[i * 4 + 2] = (float)N[2];
    T.ebas[i * 4 + 3] = (float)N[3];
  }
  // W3: out[x] = sum_m W3[x][m] * R[a3 + m], a3 = (s_all[quad0]-3)&~3.
  for (int xx = 0; xx < NE; ++xx) {
    const int a3 = (s_all[(xx >> 2) << 2] - 3) & ~3;
    for (int k = 0; k < 4; ++k) {
      const int m = s_all[xx] - 3 + k - a3;
      T.W3[xx][m] = (float)dN[xx][k];
    }
  }
  return T;
}

__constant__ Tables g_tab = make_tables();

__device__ __forceinline__ unsigned short f2bf(float f) {
  __hip_bfloat16 h = __float2bfloat16(f);              // round-to-nearest-even
  return reinterpret_cast<const unsigned short&>(h);
}

// ------------- K1: full 2D banded solve, register-staged stage 1 -------------
// CT[bc][j][i] (BF16) = sum_{d,e} Gb[i][d]*Gb[j][e]*Z[bc][i-WH+d][j-WH+e]
// Stage 1 reads Z windows DIRECTLY from global (coalesced 256B groups, 4x
// redundancy served by L1/L2); boundary handling = address clamp + zero taps.
// 13-tap window for j-quad q: w[q+2 .. q+14] of the 20-float granule window
// based at (quad_base - 8). Only LDS is the transposed stage-1 At -> 1 barrier.

__global__ __launch_bounds__(256) void k_solve2d(const float* __restrict__ Z,
                                                 unsigned short* __restrict__ CT) {
  const int it = blockIdx.x * 64;
  const int jt = blockIdx.y * 64;
  const int bc = blockIdx.z;
  const float* __restrict__ src = Z + (size_t)bc * (NN * NN);
  __shared__ float At[64][89];   // stage-1 result TRANSPOSED: At[jc][ii]
  const int tid = threadIdx.x;
  const int q4 = (tid & 15) * 4;    // quad base (jc for stage1, ic for stage2)

  { // stage 1: 13-tap along j, 80 i-rows, straight from global
    float cy[4][WT];
    #pragma unroll
    for (int q = 0; q < 4; ++q)
      #pragma unroll
      for (int d = 0; d < WT; ++d)
        cy[q][d] = g_tab.Gb[jt + q4 + q][d];
    #pragma unroll 1
    for (int p = 0; p < 5; ++p) {
      const int ii = p * 16 + (tid >> 4);
      int gi = it - 8 + ii;
      gi = (gi < 0) ? 0 : ((gi > NN - 1) ? NN - 1 : gi);   // clamp: garbage killed by stage-2 zero taps
      const float* __restrict__ rowp = &src[(size_t)gi * NN];
      float w[20];
      #pragma unroll
      for (int e = 0; e < 5; ++e) {
        int gj = jt + q4 - 8 + e * 4;                       // 4-aligned granule
        gj = (gj < 0) ? 0 : ((gj > NN - 4) ? NN - 4 : gj);  // clamp: dead granules hit zero taps
        *(float4*)&w[e * 4] = *(const float4*)&rowp[gj];
      }
      float4 a = make_float4(0.f, 0.f, 0.f, 0.f);
      #pragma unroll
      for (int d = 0; d < WT; ++d) {
        a.x += cy[0][d] * w[2 + d];
        a.y += cy[1][d] * w[3 + d];
        a.z += cy[2][d] * w[4 + d];
        a.w += cy[3][d] * w[5 + d];
      }
      At[q4 + 0][ii] = a.x;
      At[q4 + 1][ii] = a.y;
      At[q4 + 2][ii] = a.z;
      At[q4 + 3][ii] = a.w;
    }
  }
  { // stage 2: 13-tap along i; coalesced bf16 writes
    float cx[4][WT];
    #pragma unroll
    for (int q = 0; q < 4; ++q)
      #pragma unroll
      for (int d = 0; d < WT; ++d)
        cx[q][d] = g_tab.Gb[it + q4 + q][d];
    __syncthreads();
    unsigned short* __restrict__ dst = CT + (size_t)bc * (NN * NN);
    #pragma unroll 1
    for (int p = 0; p < 4; ++p) {
      const int jc = p * 16 + (tid >> 4);
      float w[20];
      #pragma unroll
      for (int e = 0; e < 5; ++e)
        *(float4*)&w[e * 4] = *(const float4*)&At[jc][q4 + e * 4];
      float4 a = make_float4(0.f, 0.f, 0.f, 0.f);
      #pragma unroll
      for (int d = 0; d < WT; ++d) {
        a.x += cx[0][d] * w[2 + d];
        a.y += cx[1][d] * w[3 + d];
        a.z += cx[2][d] * w[4 + d];
        a.w += cx[3][d] * w[5 + d];
      }
      ushort4 o;
      o.x = f2bf(a.x); o.y = f2bf(a.y); o.z = f2bf(a.z); o.w = f2bf(a.w);
      *(ushort4*)&dst[(size_t)(jt + jc) * NN + it + q4] = o;   // 8B aligned
    }
  }
}

// ------------- K2: sliding P-window eval (bf16 CT, YT=32, PLAIN stores) -------------
// P[r] = anchored 12-tap x-filter of CT row r at this thread's x-quad
// (3 ds_read_b64 + 12 unpack + 48 FMA, once per unique row). out[y] =
// 4-tap y-combine of the 4-row P window + 1 float4 store.
// Window slides 0/1 per y via wave-uniform branch, static indexing.

__global__ __launch_bounds__(256) void k_eval8(const unsigned short* __restrict__ CT,
                                               float* __restrict__ out) {
  const int b = blockIdx.x;                         // 32 y-tiles
  const int ytile = ((b & 7) << 2) | (b >> 3);      // XCD-chunked swizzle (bijective, 32)
  const int y0 = ytile * YT;
  const int bc = blockIdx.y;
  const unsigned short* __restrict__ S = CT + (size_t)bc * (NN * NN);
  __shared__ unsigned short rows[NR][528];          // 512 data + 16 zero pad (a3+11 <= 519)
  const int tid = threadIdx.x;
  const int rlo = g_tab.espan[y0] - 3;

  // load NR-row window (bf16, uint4 = 8 coefs per load)
  for (int u = tid; u < NR * 66; u += 256) {
    const int rr = u / 66, c8 = (u % 66) * 8;
    const int r = rlo + rr;
    uint4 v = make_uint4(0u, 0u, 0u, 0u);
    if (r < NN && c8 < 512) v = *(const uint4*)&S[(size_t)r * NN + c8];
    *(uint4*)&rows[rr][c8] = v;
  }

  // hoisted per-thread constants
  const int x0 = tid * 4;
  const int a3 = (g_tab.espan[x0] - 3) & ~3;        // window base (mult of 4)
  float tp[4][12];
  #pragma unroll
  for (int e = 0; e < 4; ++e)
    #pragma unroll
    for (int m = 0; m < 12; ++m)
      tp[e][m] = g_tab.W3[x0 + e][m];

  __syncthreads();

  // filtered quad of bf16 LDS row r
  auto filterP = [&](int r) -> v4f {
    uint2 q0 = *(const uint2*)&rows[r][a3];          // 8B aligned (a3 mult 4)
    uint2 q1 = *(const uint2*)&rows[r][a3 + 4];
    uint2 q2 = *(const uint2*)&rows[r][a3 + 8];
    float w[12];
    w[0]  = __uint_as_float(q0.x << 16); w[1]  = __uint_as_float(q0.x & 0xffff0000u);
    w[2]  = __uint_as_float(q0.y << 16); w[3]  = __uint_as_float(q0.y & 0xffff0000u);
    w[4]  = __uint_as_float(q1.x << 16); w[5]  = __uint_as_float(q1.x & 0xffff0000u);
    w[6]  = __uint_as_float(q1.y << 16); w[7]  = __uint_as_float(q1.y & 0xffff0000u);
    w[8]  = __uint_as_float(q2.x << 16); w[9]  = __uint_as_float(q2.x & 0xffff0000u);
    w[10] = __uint_as_float(q2.y << 16); w[11] = __uint_as_float(q2.y & 0xffff0000u);
    v4f p;
    #pragma unroll
    for (int e = 0; e < 4; ++e) {
      float s0 = 0.f, s1 = 0.f;
      #pragma unroll
      for (int m = 0; m < 12; m += 2) {
        s0 += tp[e][m]     * w[m];
        s1 += tp[e][m + 1] * w[m + 1];
      }
      p[e] = s0 + s1;
    }
    return p;
  };

  // initial window: ry(y0) = 3 -> rows 0..3
  v4f P0 = filterP(0), P1 = filterP(1), P2 = filterP(2), P3 = filterP(3);
  int prev = 3;
  float* __restrict__ O0 = out + ((size_t)bc * NE + y0) * NE + x0;
  #pragma unroll 1
  for (int k = 0; k < YT; ++k) {
    const int ry = g_tab.espan[y0 + k] - rlo;       // wave-uniform; advances 0 or 1
    if (ry != prev) {                               // slide window (static moves)
      P0 = P1; P1 = P2; P2 = P3;
      P3 = filterP(ry);
      prev = ry;
    }
    const float4 wy = *(const float4*)&g_tab.ebas[(y0 + k) * 4];
    v4f o;
    #pragma unroll
    for (int e = 0; e < 4; ++e)
      o[e] = wy.x * P0[e] + wy.y * P1[e] + wy.z * P2[e] + wy.w * P3[e];
    *(v4f*)&O0[(size_t)k * NE] = o;                 // PLAIN store (nt A/B)
  }
}

// ---------------- host launcher ----------------

extern "C" void kernel_launch(void* const* d_in, const int* in_sizes, int n_in,
                              void* d_out, int out_size, void* d_ws, size_t ws_size,
                              hipStream_t stream) {
  (void)in_sizes; (void)n_in; (void)out_size; (void)ws_size;
  const float* Z = (const float*)d_in[0];
  float* out = (float*)d_out;
  unsigned short* CT = (unsigned short*)d_ws;   // 32 MB bf16 coefficients

  k_solve2d<<<dim3(8, 8, NBC),   256, 0, stream>>>(Z,  CT);   // 2D banded solve -> bf16 CT
  k_eval8  <<<dim3(NE / YT, NBC), 256, 0, stream>>>(CT, out); // sliding P-window eval
}